// Round 13
// baseline (179.733 us; speedup 1.0000x reference)
//
#include <hip/hip_runtime.h>
#include <math.h>

typedef __bf16 bf16;
typedef __bf16 bf16x8 __attribute__((ext_vector_type(8)));
typedef __bf16 bf16x4 __attribute__((ext_vector_type(4)));
typedef __bf16 bf16x2 __attribute__((ext_vector_type(2)));
typedef float  f32x4  __attribute__((ext_vector_type(4)));
typedef unsigned int uint;

// B=16, LQ=512, LK=1024, D=512, H=8, DH=64, TEMP=0.8
#define SCQ2 0.22542110f   // 1/(8*0.8) * log2(e), folded into Q projection
#define SMREF 16.0f        // fixed softmax reference (log2 domain), in MFMA C-init

#define VMC(n) asm volatile("s_waitcnt vmcnt(" #n ")" ::: "memory")
#define BARR do { __builtin_amdgcn_s_barrier(); __builtin_amdgcn_sched_barrier(0); } while (0)

#if __has_builtin(__builtin_amdgcn_exp2f)
#define EXP2F __builtin_amdgcn_exp2f
#else
#define EXP2F exp2f
#endif

__device__ __forceinline__ void gload16(const void* g, void* l) {
  __builtin_amdgcn_global_load_lds((const __attribute__((address_space(1))) void*)g,
                                   (__attribute__((address_space(3))) void*)l, 16, 0, 0);
}

__device__ __forceinline__ uint pk2(float a, float b) {
  bf16x2 t = {(bf16)a, (bf16)b};
  return __builtin_bit_cast(uint, t);
}

union V8 { bf16x8 v; bf16x4 h[2]; uint u[4]; };

// ---------------------------------------------------------------------------
// prep+conv fused (unchanged).
// ---------------------------------------------------------------------------
__global__ void prep_k(const float* __restrict__ Wq, const float* __restrict__ Wk,
                       const float* __restrict__ Wv, const float* __restrict__ Wo,
                       bf16* __restrict__ Tq, bf16* __restrict__ Tkv, bf16* __restrict__ To,
                       const float* __restrict__ gate, const int* __restrict__ mask,
                       float* __restrict__ gfac,
                       const float* __restrict__ Qs, const float* __restrict__ KVs,
                       bf16* __restrict__ Qsb, bf16* __restrict__ KVb) {
  const int bid = blockIdx.x, tid = threadIdx.x;
  if (bid < 256) {
    const int w = bid >> 6, t = bid & 63;
    const float* W = (w == 0) ? Wq : (w == 1) ? Wk : (w == 2) ? Wv : Wo;
    bf16* T = (w == 0) ? Tq : (w == 3) ? To : Tkv;
    const int ro = (w == 2) ? 512 : 0;
    const int k0 = (t >> 3) * 64, n0 = (t & 7) * 64;
    __shared__ bf16 tl[64][72];
#pragma unroll
    for (int i = 0; i < 16; i++) {
      int s = i * 256 + tid;
      int r = s >> 6, c = s & 63;
      tl[r][c] = (bf16)W[(size_t)(k0 + r) * 512 + n0 + c];
    }
    __syncthreads();
#pragma unroll
    for (int i = 0; i < 16; i++) {
      int s = i * 256 + tid;
      int r = s >> 6, c = s & 63;
      T[(size_t)(ro + n0 + r) * 512 + k0 + c] = tl[c][r];
    }
  } else if (bid < 320) {
    int i = (bid - 256) * 256 + tid;  // 0..16383
    gfac[i] = mask[i] ? __expf(1.25f * __logf(gate[i])) : 0.0f;
  } else {
    const float* s;
    bf16* d;
    size_t i;
    if (bid < 2368) { s = Qs; d = Qsb; i = ((size_t)(bid - 320) * 256 + tid) * 8; }
    else            { s = KVs; d = KVb; i = ((size_t)(bid - 2368) * 256 + tid) * 8; }
    f32x4 a = *(const f32x4*)(s + i);
    f32x4 b = *(const f32x4*)(s + i + 4);
    bf16x8 o = {(bf16)a[0], (bf16)a[1], (bf16)a[2], (bf16)a[3],
                (bf16)b[0], (bf16)b[1], (bf16)b[2], (bf16)b[3]};
    *(bf16x8*)(d + i) = o;
  }
}

// ---------------------------------------------------------------------------
// KV projection, 8-phase schedule (unchanged). Tile 256x256, BK=32, 8 waves.
// ---------------------------------------------------------------------------
__global__ __launch_bounds__(512, 2) void gemm_kv8(
    const bf16* __restrict__ A, const bf16* __restrict__ Bt,
    const float* __restrict__ kb, const float* __restrict__ vb,
    const float* __restrict__ gfac, bf16* __restrict__ K_out, bf16* __restrict__ V_out) {
  const int tid = threadIdx.x, w = tid >> 6, l = tid & 63;
  const int lg = l >> 4, lr = l & 15;
  const int bid = (int)(blockIdx.x & 7) * 32 + (int)(blockIdx.x >> 3);  // XCD swizzle
  const int bm = (bid >> 2) * 256;
  const int bn = (bid & 3) * 256;
  const int wm = w >> 2, wn = w & 3;

  __shared__ __align__(16) bf16 AB[2][16384];  // per buf: A[256][32] @0, B[256][32] @8192

  const int lrow = l >> 2;
  const int cs = (l & 3) ^ ((l >> 3) & 3);

  f32x4 acc[8][4];
#pragma unroll
  for (int i = 0; i < 8; i++)
#pragma unroll
    for (int j = 0; j < 4; j++) acc[i][j] = (f32x4){0.f, 0.f, 0.f, 0.f};

  auto stA = [&](int p, int u, int kt) {
    const int rb = (w >> 2) * 128 + u * 64 + (w & 3) * 16;
    gload16(A + (size_t)(bm + rb + lrow) * 512 + kt * 32 + cs * 8, &AB[p][rb * 32]);
  };
  auto stB = [&](int p, int u, int kt) {
    const int rb = (w >> 1) * 64 + u * 32 + (w & 1) * 16;
    gload16(Bt + (size_t)(bn + rb + lrow) * 512 + kt * 32 + cs * 8, &AB[p][8192 + rb * 32]);
  };

  bf16x8 aA[4], bb0[2], bb1[2];
#define RDA(p, mh)                                                                   \
  _Pragma("unroll") for (int m2 = 0; m2 < 4; m2++) {                                 \
    const int row = wm * 128 + (mh) * 64 + m2 * 16 + lr;                             \
    aA[m2] = *(const bf16x8*)(&AB[p][row * 32 + ((lg ^ ((row >> 1) & 3)) * 8)]);     \
  }
#define RDB(p, nh, dst)                                                              \
  _Pragma("unroll") for (int n2 = 0; n2 < 2; n2++) {                                 \
    const int row = wn * 64 + (nh) * 32 + n2 * 16 + lr;                              \
    dst[n2] = *(const bf16x8*)(&AB[p][8192 + row * 32 + ((lg ^ ((row >> 1) & 3)) * 8)]); \
  }
#define MM(mh, nh, bbv)                                                              \
  __builtin_amdgcn_s_setprio(1);                                                     \
  _Pragma("unroll") for (int m2 = 0; m2 < 4; m2++)                                   \
  _Pragma("unroll") for (int n2 = 0; n2 < 2; n2++)                                   \
    acc[(mh) * 4 + m2][(nh) * 2 + n2] =                                              \
        __builtin_amdgcn_mfma_f32_16x16x32_bf16(aA[m2], bbv[n2],                     \
                                                acc[(mh) * 4 + m2][(nh) * 2 + n2], 0, 0, 0); \
  __builtin_amdgcn_s_setprio(0);

  stA(0, 0, 0); stB(0, 0, 0); stA(0, 1, 0); stB(0, 1, 0);
  stA(1, 0, 1); stB(1, 0, 1);
  VMC(4);
  BARR;

  for (int i = 0; i < 8; ++i) {
    const bool last = (i == 7);
    const int k1 = 2 * i + 1, k2 = 2 * i + 2, k3 = 2 * i + 3;
    stA(1, 1, k1); stB(1, 1, k1);
    RDA(0, 0); RDB(0, 0, bb0);
    MM(0, 0, bb0);
    VMC(4); BARR;
    RDB(0, 1, bb1);
    MM(0, 1, bb1);
    BARR;
    if (!last) stA(0, 0, k2);
    RDA(0, 1);
    MM(1, 0, bb0);
    BARR;
    if (!last) stB(0, 0, k2);
    MM(1, 1, bb1);
    if (last) { VMC(2); } else { VMC(4); }
    BARR;
    if (!last) { stA(0, 1, k2); stB(0, 1, k2); }
    RDA(1, 0); RDB(1, 0, bb0);
    MM(0, 0, bb0);
    if (last) { VMC(0); } else { VMC(4); }
    BARR;
    RDB(1, 1, bb1);
    MM(0, 1, bb1);
    BARR;
    if (!last) stA(1, 0, k3);
    RDA(1, 1);
    MM(1, 0, bb0);
    BARR;
    if (!last) stB(1, 0, k3);
    MM(1, 1, bb1);
    VMC(4); BARR;
  }
#undef RDA
#undef RDB
#undef MM

  if (bn < 512) {
#pragma unroll
    for (int mf = 0; mf < 8; mf++) {
#pragma unroll
      for (int nf = 0; nf < 4; nf++) {
        f32x4 c = acc[mf][nf];
        const int n = bn + wn * 64 + nf * 16 + lr;
        const int m0 = bm + wm * 128 + mf * 16 + lg * 4;
        const float bias = kb[n];
#pragma unroll
        for (int r = 0; r < 4; r++) K_out[(size_t)(m0 + r) * 512 + n] = (bf16)(c[r] + bias);
      }
    }
  } else {
#pragma unroll
    for (int mf = 0; mf < 8; mf++) {
#pragma unroll
      for (int nf = 0; nf < 4; nf++) {
        f32x4 c = acc[mf][nf];
        const int n = bn + wn * 64 + nf * 16 + lr;
        const int m0 = bm + wm * 128 + mf * 16 + lg * 4;
        const int nn = n - 512;
        const int hh = nn >> 6, dd = nn & 63;
        const int bb = m0 >> 10, key = m0 & 1023;
        const int u = key & 31;
        const int keyp = (key & ~31) + ((u & 15) >> 2) * 8 + ((u >> 4) & 1) * 4;
        const float bias = vb[nn];
        f32x4 g4 = *(const f32x4*)(gfac + m0);
        bf16x4 w4 = {(bf16)((c[0] + bias) * g4[0]), (bf16)((c[1] + bias) * g4[1]),
                     (bf16)((c[2] + bias) * g4[2]), (bf16)((c[3] + bias) * g4[3])};
        *(bf16x4*)(V_out + ((size_t)((bb * 8 + hh) * 64 + dd)) * 1024 + keyp) = w4;
      }
    }
  }
}

// ---------------------------------------------------------------------------
// Q/O projection GEMM: 3-buffer counted-vmcnt pipeline (unchanged).
// ---------------------------------------------------------------------------
template <int OM, int NT, int CHUNK>
__global__ __launch_bounds__(256, 2) void gemm_k(
    const bf16* __restrict__ A, const bf16* __restrict__ Bt,
    const float* __restrict__ b0, void* __restrict__ C0, float scale) {
  const int tid = threadIdx.x, w = tid >> 6, l = tid & 63;
  const int lg = l >> 4, lr = l & 15;
  const int bid = (int)(blockIdx.x & 7) * CHUNK + (int)(blockIdx.x >> 3);
  const int bm = (bid / NT) * 64;
  const int bn = (bid % NT) * 128;
  const int wr = (w >> 1) * 32, wc = (w & 1) * 64;
  __shared__ __align__(16) bf16 As[3][64][32];
  __shared__ __align__(16) bf16 Bs[3][128][32];
  const int r16 = l >> 2;
  const int cs = (l & 3) ^ ((l >> 3) & 3);

  f32x4 acc[2][4];
#pragma unroll
  for (int i = 0; i < 2; i++)
#pragma unroll
    for (int j = 0; j < 4; j++) acc[i][j] = (f32x4){0.f, 0.f, 0.f, 0.f};

  auto stage = [&](int buf, int kt) {
    gload16(A + (size_t)(bm + w * 16 + r16) * 512 + kt * 32 + cs * 8, &As[buf][w * 16][0]);
#pragma unroll
    for (int j = 0; j < 2; j++)
      gload16(Bt + (size_t)(bn + w * 32 + j * 16 + r16) * 512 + kt * 32 + cs * 8,
              &Bs[buf][w * 32 + j * 16][0]);
  };

  stage(0, 0);
  stage(1, 1);
  for (int t = 0; t < 16; ++t) {
    const int buf = t % 3;
    if (t == 15) { VMC(0); } else { VMC(3); }
    BARR;
    if (t < 14) stage((t + 2) % 3, t + 2);
    bf16x8 af[2], bfr[4];
#pragma unroll
    for (int mf = 0; mf < 2; mf++) {
      const int row = wr + mf * 16 + lr;
      af[mf] = *(const bf16x8*)(&As[buf][row][(lg ^ ((row >> 1) & 3)) * 8]);
    }
#pragma unroll
    for (int nf = 0; nf < 4; nf++) {
      const int row = wc + nf * 16 + lr;
      bfr[nf] = *(const bf16x8*)(&Bs[buf][row][(lg ^ ((row >> 1) & 3)) * 8]);
    }
    __builtin_amdgcn_s_setprio(1);
#pragma unroll
    for (int mf = 0; mf < 2; mf++)
#pragma unroll
      for (int nf = 0; nf < 4; nf++)
        acc[mf][nf] = __builtin_amdgcn_mfma_f32_16x16x32_bf16(af[mf], bfr[nf], acc[mf][nf], 0, 0, 0);
    __builtin_amdgcn_s_setprio(0);
  }

#pragma unroll
  for (int mf = 0; mf < 2; mf++) {
#pragma unroll
    for (int nf = 0; nf < 4; nf++) {
      f32x4 c = acc[mf][nf];
      const int n = bn + wc + nf * 16 + lr;
      const int m0 = bm + wr + mf * 16 + lg * 4;
      const float bias = b0[n];
      if constexpr (OM == 0) {
        bf16* C = (bf16*)C0;
#pragma unroll
        for (int r = 0; r < 4; r++) C[(size_t)(m0 + r) * 512 + n] = (bf16)((c[r] + bias) * scale);
      } else {
        float* C = (float*)C0;
#pragma unroll
        for (int r = 0; r < 4; r++) C[(size_t)(m0 + r) * 512 + n] = c[r] + bias;
      }
    }
  }
}

// ---------------------------------------------------------------------------
// Fused attention v10: direct-register K/V, SPILL-FREE retry of v9.
// Fixes vs v9: __launch_bounds__(512,1) (256-VGPR budget, v9's (512,2)
// capped at 128 and spilled 114MB to scratch) and fully static register
// indexing (named kfA/kfB, chunk loop unrolled x2 — rule #20).
// Block=(b,h,128q), 8 waves = split-K(2 halves of 512 keys) x 4 waves x
// 32 q (2 slabs). No LDS staging, no barriers in main loop; fixed-ref
// softmax => halves exactly additive; merge via LDS at end. Grid 512.
// ---------------------------------------------------------------------------
__global__ __launch_bounds__(512, 1) void attn_k(
    const bf16* __restrict__ Q, const bf16* __restrict__ Kb,
    const bf16* __restrict__ Vt, const float* __restrict__ gfac,
    bf16* __restrict__ ctx) {
  const int tid = threadIdx.x, w = tid >> 6, l = tid & 63;
  const int lg = l >> 4, lr = l & 15;
  const int ks = w >> 2, wl = w & 3;  // key-half, wave-in-half
  const int bid = (int)(blockIdx.x & 7) * 64 + (int)(blockIdx.x >> 3);  // XCD swizzle
  const int qb = bid & 3, h = (bid >> 2) & 7, b = bid >> 5;
  const int q0 = qb * 128;

  __shared__ __align__(16) f32x4 Om[2048];  // 32 KB merge scratch
  __shared__ __align__(16) float Lp[512];   // 2 KB

  bf16x8 qf[2][2];
#pragma unroll
  for (int s = 0; s < 2; s++) {
    const bf16* qp = Q + (size_t)(b * 512 + q0 + wl * 32 + s * 16 + lr) * 512 + h * 64;
    qf[s][0] = *(const bf16x8*)(qp + lg * 8);
    qf[s][1] = *(const bf16x8*)(qp + 32 + lg * 8);
  }

  f32x4 o[2][4];
#pragma unroll
  for (int s = 0; s < 2; s++)
#pragma unroll
    for (int i = 0; i < 4; i++) o[s][i] = (f32x4){0.f, 0.f, 0.f, 0.f};
  f32x4 lacc[2] = {(f32x4){0.f, 0.f, 0.f, 0.f}, (f32x4){0.f, 0.f, 0.f, 0.f}};

  const bf16* Kbh = Kb + ((size_t)(b * 1024 + ks * 512)) * 512 + h * 64;
  const bf16* Vbh = Vt + ((size_t)(b * 8 + h) * 64) * 1024 + ks * 512;
  const float* gbh = gfac + b * 1024 + ks * 512;

  bf16x8 kfA[4][2], kfB[4][2];

  auto loadK = [&](int t, bf16x8 (&dst)[4][2]) {
#pragma unroll
    for (int f = 0; f < 4; f++) {
      const size_t ro = (size_t)(t * 64 + f * 16 + lr) * 512;
      dst[f][0] = *(const bf16x8*)(Kbh + ro + lg * 8);
      dst[f][1] = *(const bf16x8*)(Kbh + ro + 32 + lg * 8);
    }
  };

  auto body = [&](int t, bf16x8 (&kc)[4][2], bf16x8 (&kn)[4][2], bool pre) {
    // V + gfac for this chunk, issued early (consumed after QK+exp2)
    bf16x8 vf[4][2];
#pragma unroll
    for (int od = 0; od < 4; od++) {
      const size_t ro = (size_t)(od * 16 + lr) * 1024 + t * 64;
      vf[od][0] = *(const bf16x8*)(Vbh + ro + lg * 8);
      vf[od][1] = *(const bf16x8*)(Vbh + ro + (4 + lg) * 8);
    }
    f32x4 gvv[4];
#pragma unroll
    for (int f = 0; f < 4; f++) gvv[f] = *(const f32x4*)(gbh + t * 64 + f * 16 + lg * 4);
    if (pre) loadK(t + 1, kn);

    V8 pb[2][2];
#pragma unroll
    for (int s = 0; s < 2; s++) {
      f32x4 s4[4];
      __builtin_amdgcn_s_setprio(1);
#pragma unroll
      for (int f = 0; f < 4; f++) {
        f32x4 z = (f32x4){-SMREF, -SMREF, -SMREF, -SMREF};
        z = __builtin_amdgcn_mfma_f32_16x16x32_bf16(kc[f][0], qf[s][0], z, 0, 0, 0);
        s4[f] = __builtin_amdgcn_mfma_f32_16x16x32_bf16(kc[f][1], qf[s][1], z, 0, 0, 0);
      }
      __builtin_amdgcn_s_setprio(0);
      float p[4][4];
#pragma unroll
      for (int f = 0; f < 4; f++)
#pragma unroll
        for (int r = 0; r < 4; r++) p[f][r] = EXP2F(s4[f][r]);
#pragma unroll
      for (int f = 0; f < 4; f++)
#pragma unroll
        for (int r = 0; r < 4; r++) lacc[s][r] = fmaf(p[f][r], gvv[f][r], lacc[s][r]);
      pb[s][0].u[0] = pk2(p[0][0], p[0][1]); pb[s][0].u[1] = pk2(p[0][2], p[0][3]);
      pb[s][0].u[2] = pk2(p[1][0], p[1][1]); pb[s][0].u[3] = pk2(p[1][2], p[1][3]);
      pb[s][1].u[0] = pk2(p[2][0], p[2][1]); pb[s][1].u[1] = pk2(p[2][2], p[2][3]);
      pb[s][1].u[2] = pk2(p[3][0], p[3][1]); pb[s][1].u[3] = pk2(p[3][2], p[3][3]);
    }

    __builtin_amdgcn_s_setprio(1);
#pragma unroll
    for (int od = 0; od < 4; od++) {
#pragma unroll
      for (int s = 0; s < 2; s++) {
        o[s][od] = __builtin_amdgcn_mfma_f32_16x16x32_bf16(vf[od][0], pb[s][0].v, o[s][od], 0, 0, 0);
        o[s][od] = __builtin_amdgcn_mfma_f32_16x16x32_bf16(vf[od][1], pb[s][1].v, o[s][od], 0, 0, 0);
      }
    }
    __builtin_amdgcn_s_setprio(0);
  };

  loadK(0, kfA);
#pragma unroll
  for (int tt = 0; tt < 8; tt += 2) {
    body(tt, kfA, kfB, true);
    body(tt + 1, kfB, kfA, tt + 2 < 8);
  }

  // --- merge halves through LDS (only sync in the kernel) ---
  __syncthreads();
  if (ks == 1) {
    const int base = (wl * 64 + l) * 8;
#pragma unroll
    for (int s = 0; s < 2; s++)
#pragma unroll
      for (int od = 0; od < 4; od++) Om[base + ((s * 4 + od) ^ (l & 7))] = o[s][od];
#pragma unroll
    for (int s = 0; s < 2; s++)
      Lp[(wl * 64 + l) * 2 + s] = (lacc[s][0] + lacc[s][1]) + (lacc[s][2] + lacc[s][3]);
  }
  __syncthreads();
  if (ks == 0) {
    const int base = (wl * 64 + l) * 8;
#pragma unroll
    for (int s = 0; s < 2; s++)
#pragma unroll
      for (int od = 0; od < 4; od++) o[s][od] += Om[base + ((s * 4 + od) ^ (l & 7))];
#pragma unroll
    for (int s = 0; s < 2; s++) {
      float lp = (lacc[s][0] + lacc[s][1]) + (lacc[s][2] + lacc[s][3]) +
                 Lp[(wl * 64 + l) * 2 + s];
      lp += __shfl_xor(lp, 16);
      lp += __shfl_xor(lp, 32);
      const float inv = 1.0f / lp;
      bf16* cp = ctx + (size_t)(b * 512 + q0 + wl * 32 + s * 16 + lr) * 512 + h * 64;
#pragma unroll
      for (int od = 0; od < 4; od++)
#pragma unroll
        for (int r = 0; r < 4; r++) cp[od * 16 + lg * 4 + r] = (bf16)(o[s][od][r] * inv);
    }
  }
}

// ---------------------------------------------------------------------------
extern "C" void kernel_launch(void* const* d_in, const int* in_sizes, int n_in,
                              void* d_out, int out_size, void* d_ws, size_t ws_size,
                              hipStream_t stream) {
  (void)in_sizes; (void)n_in; (void)out_size; (void)ws_size;
  const float* Q_src = (const float*)d_in[0];
  const float* KV_src = (const float*)d_in[1];
  const float* gate = (const float*)d_in[2];
  const int* mask = (const int*)d_in[3];
  const float* Wq = (const float*)d_in[4];
  const float* bq = (const float*)d_in[5];
  const float* Wk = (const float*)d_in[6];
  const float* bk = (const float*)d_in[7];
  const float* Wv = (const float*)d_in[8];
  const float* bv = (const float*)d_in[9];
  const float* Wo = (const float*)d_in[10];
  const float* bo = (const float*)d_in[11];
  float* out = (float*)d_out;

  char* ws = (char*)d_ws;
  size_t off = 0;
  auto alloc = [&](size_t bytes) {
    char* p = ws + off;
    off += (bytes + 255) & ~(size_t)255;
    return p;
  };
  bf16* Wtq = (bf16*)alloc(512 * 512 * 2);
  bf16* Btkv = (bf16*)alloc(1024 * 512 * 2);
  bf16* Wto = (bf16*)alloc(512 * 512 * 2);
  float* gfac = (float*)alloc(16384 * 4);
  bf16* Qsb = (bf16*)alloc((size_t)8192 * 512 * 2);
  bf16* KVb = (bf16*)alloc((size_t)16384 * 512 * 2);  // reused as Cx after KV GEMM
  bf16* Qb = (bf16*)alloc((size_t)8192 * 512 * 2);
  bf16* Kb = (bf16*)alloc((size_t)16384 * 512 * 2);
  bf16* Vt = (bf16*)alloc((size_t)16384 * 512 * 2);
  bf16* Cx = KVb;

  prep_k<<<6464, 256, 0, stream>>>(Wq, Wk, Wv, Wo, Wtq, Btkv, Wto, gate, mask, gfac,
                                   Q_src, KV_src, Qsb, KVb);
  // K+V fused projection: [16384,512] @ [512,1024], 8-phase 256x256 tiles
  gemm_kv8<<<256, 512, 0, stream>>>(KVb, Btkv, bk, bv, gfac, Kb, Vt);
  // Q projection (scale folds softmax 1/6.4 and log2e)
  gemm_k<0, 4, 64><<<512, 256, 0, stream>>>(Qsb, Wtq, bq, Qb, SCQ2);
  attn_k<<<512, 512, 0, stream>>>(Qb, Kb, Vt, gfac, Cx);
  // O projection -> f32 out
  gemm_k<2, 4, 64><<<512, 256, 0, stream>>>(Cx, Wto, bo, out, 1.0f);
}

// Round 14
// 84.847 us; speedup vs baseline: 2.1183x; 2.1183x over previous
//
#include <hip/hip_runtime.h>
#include <math.h>

typedef __bf16 bf16;
typedef __bf16 bf16x8 __attribute__((ext_vector_type(8)));
typedef __bf16 bf16x4 __attribute__((ext_vector_type(4)));
typedef __bf16 bf16x2 __attribute__((ext_vector_type(2)));
typedef float  f32x4  __attribute__((ext_vector_type(4)));
typedef unsigned int uint;

// B=16, LQ=512, LK=1024, D=512, H=8, DH=64, TEMP=0.8
#define SCQ2 0.22542110f   // 1/(8*0.8) * log2(e), folded into Q projection
#define SMREF 16.0f        // fixed softmax reference (log2 domain), in MFMA C-init

#define VMC(n) asm volatile("s_waitcnt vmcnt(" #n ")" ::: "memory")
#define BARR do { __builtin_amdgcn_s_barrier(); __builtin_amdgcn_sched_barrier(0); } while (0)

#if __has_builtin(__builtin_amdgcn_exp2f)
#define EXP2F __builtin_amdgcn_exp2f
#else
#define EXP2F exp2f
#endif

__device__ __forceinline__ void gload16(const void* g, void* l) {
  __builtin_amdgcn_global_load_lds((const __attribute__((address_space(1))) void*)g,
                                   (__attribute__((address_space(3))) void*)l, 16, 0, 0);
}

__device__ __forceinline__ uint pk2(float a, float b) {
  bf16x2 t = {(bf16)a, (bf16)b};
  return __builtin_bit_cast(uint, t);
}

union V8 { bf16x8 v; bf16x4 h[2]; uint u[4]; };

// ---------------------------------------------------------------------------
// prep+conv fused.
// ---------------------------------------------------------------------------
__global__ void prep_k(const float* __restrict__ Wq, const float* __restrict__ Wk,
                       const float* __restrict__ Wv, const float* __restrict__ Wo,
                       bf16* __restrict__ Tq, bf16* __restrict__ Tkv, bf16* __restrict__ To,
                       const float* __restrict__ gate, const int* __restrict__ mask,
                       float* __restrict__ gfac,
                       const float* __restrict__ Qs, const float* __restrict__ KVs,
                       bf16* __restrict__ Qsb, bf16* __restrict__ KVb) {
  const int bid = blockIdx.x, tid = threadIdx.x;
  if (bid < 256) {
    const int w = bid >> 6, t = bid & 63;
    const float* W = (w == 0) ? Wq : (w == 1) ? Wk : (w == 2) ? Wv : Wo;
    bf16* T = (w == 0) ? Tq : (w == 3) ? To : Tkv;
    const int ro = (w == 2) ? 512 : 0;
    const int k0 = (t >> 3) * 64, n0 = (t & 7) * 64;
    __shared__ bf16 tl[64][72];
#pragma unroll
    for (int i = 0; i < 16; i++) {
      int s = i * 256 + tid;
      int r = s >> 6, c = s & 63;
      tl[r][c] = (bf16)W[(size_t)(k0 + r) * 512 + n0 + c];
    }
    __syncthreads();
#pragma unroll
    for (int i = 0; i < 16; i++) {
      int s = i * 256 + tid;
      int r = s >> 6, c = s & 63;
      T[(size_t)(ro + n0 + r) * 512 + k0 + c] = tl[c][r];
    }
  } else if (bid < 320) {
    int i = (bid - 256) * 256 + tid;  // 0..16383
    gfac[i] = mask[i] ? __expf(1.25f * __logf(gate[i])) : 0.0f;
  } else {
    const float* s;
    bf16* d;
    size_t i;
    if (bid < 2368) { s = Qs; d = Qsb; i = ((size_t)(bid - 320) * 256 + tid) * 8; }
    else            { s = KVs; d = KVb; i = ((size_t)(bid - 2368) * 256 + tid) * 8; }
    f32x4 a = *(const f32x4*)(s + i);
    f32x4 b = *(const f32x4*)(s + i + 4);
    bf16x8 o = {(bf16)a[0], (bf16)a[1], (bf16)a[2], (bf16)a[3],
                (bf16)b[0], (bf16)b[1], (bf16)b[2], (bf16)b[3]};
    *(bf16x8*)(d + i) = o;
  }
}

// ---------------------------------------------------------------------------
// KV projection, 8-phase schedule. Tile 256x256, BK=32, 8 waves.
// ---------------------------------------------------------------------------
__global__ __launch_bounds__(512, 2) void gemm_kv8(
    const bf16* __restrict__ A, const bf16* __restrict__ Bt,
    const float* __restrict__ kb, const float* __restrict__ vb,
    const float* __restrict__ gfac, bf16* __restrict__ K_out, bf16* __restrict__ V_out) {
  const int tid = threadIdx.x, w = tid >> 6, l = tid & 63;
  const int lg = l >> 4, lr = l & 15;
  const int bid = (int)(blockIdx.x & 7) * 32 + (int)(blockIdx.x >> 3);  // XCD swizzle
  const int bm = (bid >> 2) * 256;
  const int bn = (bid & 3) * 256;
  const int wm = w >> 2, wn = w & 3;

  __shared__ __align__(16) bf16 AB[2][16384];  // per buf: A[256][32] @0, B[256][32] @8192

  const int lrow = l >> 2;
  const int cs = (l & 3) ^ ((l >> 3) & 3);

  f32x4 acc[8][4];
#pragma unroll
  for (int i = 0; i < 8; i++)
#pragma unroll
    for (int j = 0; j < 4; j++) acc[i][j] = (f32x4){0.f, 0.f, 0.f, 0.f};

  auto stA = [&](int p, int u, int kt) {
    const int rb = (w >> 2) * 128 + u * 64 + (w & 3) * 16;
    gload16(A + (size_t)(bm + rb + lrow) * 512 + kt * 32 + cs * 8, &AB[p][rb * 32]);
  };
  auto stB = [&](int p, int u, int kt) {
    const int rb = (w >> 1) * 64 + u * 32 + (w & 1) * 16;
    gload16(Bt + (size_t)(bn + rb + lrow) * 512 + kt * 32 + cs * 8, &AB[p][8192 + rb * 32]);
  };

  bf16x8 aA[4], bb0[2], bb1[2];
#define RDA(p, mh)                                                                   \
  _Pragma("unroll") for (int m2 = 0; m2 < 4; m2++) {                                 \
    const int row = wm * 128 + (mh) * 64 + m2 * 16 + lr;                             \
    aA[m2] = *(const bf16x8*)(&AB[p][row * 32 + ((lg ^ ((row >> 1) & 3)) * 8)]);     \
  }
#define RDB(p, nh, dst)                                                              \
  _Pragma("unroll") for (int n2 = 0; n2 < 2; n2++) {                                 \
    const int row = wn * 64 + (nh) * 32 + n2 * 16 + lr;                              \
    dst[n2] = *(const bf16x8*)(&AB[p][8192 + row * 32 + ((lg ^ ((row >> 1) & 3)) * 8)]); \
  }
#define MM(mh, nh, bbv)                                                              \
  __builtin_amdgcn_s_setprio(1);                                                     \
  _Pragma("unroll") for (int m2 = 0; m2 < 4; m2++)                                   \
  _Pragma("unroll") for (int n2 = 0; n2 < 2; n2++)                                   \
    acc[(mh) * 4 + m2][(nh) * 2 + n2] =                                              \
        __builtin_amdgcn_mfma_f32_16x16x32_bf16(aA[m2], bbv[n2],                     \
                                                acc[(mh) * 4 + m2][(nh) * 2 + n2], 0, 0, 0); \
  __builtin_amdgcn_s_setprio(0);

  stA(0, 0, 0); stB(0, 0, 0); stA(0, 1, 0); stB(0, 1, 0);
  stA(1, 0, 1); stB(1, 0, 1);
  VMC(4);
  BARR;

  for (int i = 0; i < 8; ++i) {
    const bool last = (i == 7);
    const int k1 = 2 * i + 1, k2 = 2 * i + 2, k3 = 2 * i + 3;
    stA(1, 1, k1); stB(1, 1, k1);
    RDA(0, 0); RDB(0, 0, bb0);
    MM(0, 0, bb0);
    VMC(4); BARR;
    RDB(0, 1, bb1);
    MM(0, 1, bb1);
    BARR;
    if (!last) stA(0, 0, k2);
    RDA(0, 1);
    MM(1, 0, bb0);
    BARR;
    if (!last) stB(0, 0, k2);
    MM(1, 1, bb1);
    if (last) { VMC(2); } else { VMC(4); }
    BARR;
    if (!last) { stA(0, 1, k2); stB(0, 1, k2); }
    RDA(1, 0); RDB(1, 0, bb0);
    MM(0, 0, bb0);
    if (last) { VMC(0); } else { VMC(4); }
    BARR;
    RDB(1, 1, bb1);
    MM(0, 1, bb1);
    BARR;
    if (!last) stA(1, 0, k3);
    RDA(1, 1);
    MM(1, 0, bb0);
    BARR;
    if (!last) stB(1, 0, k3);
    MM(1, 1, bb1);
    VMC(4); BARR;
  }
#undef RDA
#undef RDB
#undef MM

  if (bn < 512) {
#pragma unroll
    for (int mf = 0; mf < 8; mf++) {
#pragma unroll
      for (int nf = 0; nf < 4; nf++) {
        f32x4 c = acc[mf][nf];
        const int n = bn + wn * 64 + nf * 16 + lr;
        const int m0 = bm + wm * 128 + mf * 16 + lg * 4;
        const float bias = kb[n];
#pragma unroll
        for (int r = 0; r < 4; r++) K_out[(size_t)(m0 + r) * 512 + n] = (bf16)(c[r] + bias);
      }
    }
  } else {
#pragma unroll
    for (int mf = 0; mf < 8; mf++) {
#pragma unroll
      for (int nf = 0; nf < 4; nf++) {
        f32x4 c = acc[mf][nf];
        const int n = bn + wn * 64 + nf * 16 + lr;
        const int m0 = bm + wm * 128 + mf * 16 + lg * 4;
        const int nn = n - 512;
        const int hh = nn >> 6, dd = nn & 63;
        const int bb = m0 >> 10, key = m0 & 1023;
        const int u = key & 31;
        const int keyp = (key & ~31) + ((u & 15) >> 2) * 8 + ((u >> 4) & 1) * 4;
        const float bias = vb[nn];
        f32x4 g4 = *(const f32x4*)(gfac + m0);
        bf16x4 w4 = {(bf16)((c[0] + bias) * g4[0]), (bf16)((c[1] + bias) * g4[1]),
                     (bf16)((c[2] + bias) * g4[2]), (bf16)((c[3] + bias) * g4[3])};
        *(bf16x4*)(V_out + ((size_t)((bb * 8 + hh) * 64 + dd)) * 1024 + keyp) = w4;
      }
    }
  }
}

// ---------------------------------------------------------------------------
// Q/O projection GEMM: 3-buffer counted-vmcnt pipeline.
// ---------------------------------------------------------------------------
template <int OM, int NT, int CHUNK>
__global__ __launch_bounds__(256, 2) void gemm_k(
    const bf16* __restrict__ A, const bf16* __restrict__ Bt,
    const float* __restrict__ b0, void* __restrict__ C0, float scale) {
  const int tid = threadIdx.x, w = tid >> 6, l = tid & 63;
  const int lg = l >> 4, lr = l & 15;
  const int bid = (int)(blockIdx.x & 7) * CHUNK + (int)(blockIdx.x >> 3);
  const int bm = (bid / NT) * 64;
  const int bn = (bid % NT) * 128;
  const int wr = (w >> 1) * 32, wc = (w & 1) * 64;
  __shared__ __align__(16) bf16 As[3][64][32];
  __shared__ __align__(16) bf16 Bs[3][128][32];
  const int r16 = l >> 2;
  const int cs = (l & 3) ^ ((l >> 3) & 3);

  f32x4 acc[2][4];
#pragma unroll
  for (int i = 0; i < 2; i++)
#pragma unroll
    for (int j = 0; j < 4; j++) acc[i][j] = (f32x4){0.f, 0.f, 0.f, 0.f};

  auto stage = [&](int buf, int kt) {
    gload16(A + (size_t)(bm + w * 16 + r16) * 512 + kt * 32 + cs * 8, &As[buf][w * 16][0]);
#pragma unroll
    for (int j = 0; j < 2; j++)
      gload16(Bt + (size_t)(bn + w * 32 + j * 16 + r16) * 512 + kt * 32 + cs * 8,
              &Bs[buf][w * 32 + j * 16][0]);
  };

  stage(0, 0);
  stage(1, 1);
  for (int t = 0; t < 16; ++t) {
    const int buf = t % 3;
    if (t == 15) { VMC(0); } else { VMC(3); }
    BARR;
    if (t < 14) stage((t + 2) % 3, t + 2);
    bf16x8 af[2], bfr[4];
#pragma unroll
    for (int mf = 0; mf < 2; mf++) {
      const int row = wr + mf * 16 + lr;
      af[mf] = *(const bf16x8*)(&As[buf][row][(lg ^ ((row >> 1) & 3)) * 8]);
    }
#pragma unroll
    for (int nf = 0; nf < 4; nf++) {
      const int row = wc + nf * 16 + lr;
      bfr[nf] = *(const bf16x8*)(&Bs[buf][row][(lg ^ ((row >> 1) & 3)) * 8]);
    }
    __builtin_amdgcn_s_setprio(1);
#pragma unroll
    for (int mf = 0; mf < 2; mf++)
#pragma unroll
      for (int nf = 0; nf < 4; nf++)
        acc[mf][nf] = __builtin_amdgcn_mfma_f32_16x16x32_bf16(af[mf], bfr[nf], acc[mf][nf], 0, 0, 0);
    __builtin_amdgcn_s_setprio(0);
  }

#pragma unroll
  for (int mf = 0; mf < 2; mf++) {
#pragma unroll
    for (int nf = 0; nf < 4; nf++) {
      f32x4 c = acc[mf][nf];
      const int n = bn + wc + nf * 16 + lr;
      const int m0 = bm + wr + mf * 16 + lg * 4;
      const float bias = b0[n];
      if constexpr (OM == 0) {
        bf16* C = (bf16*)C0;
#pragma unroll
        for (int r = 0; r < 4; r++) C[(size_t)(m0 + r) * 512 + n] = (bf16)((c[r] + bias) * scale);
      } else {
        float* C = (float*)C0;
#pragma unroll
        for (int r = 0; r < 4; r++) C[(size_t)(m0 + r) * 512 + n] = c[r] + bias;
      }
    }
  }
}

// ---------------------------------------------------------------------------
// Fused attention (best verified: round-10 v7). Block = (b,h,256q), 8 waves
// x 32 q (2 slabs). Fixed-ref softmax with -SMREF folded into QK MFMA C-init;
// 128-key chunks (2 subtiles per barrier interval); 2-deep K/V double buffer
// via preswizzled global_load_lds; stage at chunk top, VMC(0) at chunk end;
// permuted-Vt PV; gfac in LDS. Grid 256 -> 1 block/CU.
// ---------------------------------------------------------------------------
__global__ __launch_bounds__(512, 1) void attn_k(
    const bf16* __restrict__ Q, const bf16* __restrict__ Kb,
    const bf16* __restrict__ Vt, const float* __restrict__ gfac,
    bf16* __restrict__ ctx) {
  const int tid = threadIdx.x, w = tid >> 6, l = tid & 63;
  const int lg = l >> 4, lr = l & 15;
  const int bid = (int)(blockIdx.x & 7) * 32 + (int)(blockIdx.x >> 3);  // XCD swizzle
  const int qb = bid & 1, h = (bid >> 1) & 7, b = bid >> 4;
  const int q0 = qb * 256;

  __shared__ __align__(16) bf16 Ks[2][2][64][64];  // [buf][sub] 32 KB
  __shared__ __align__(16) bf16 Vs[2][2][64][64];  // 32 KB
  __shared__ __align__(16) float gfs[1024];        // 4 KB

  bf16x8 qf[2][2];
#pragma unroll
  for (int s = 0; s < 2; s++) {
    const bf16* qp = Q + (size_t)(b * 512 + q0 + w * 32 + s * 16 + lr) * 512 + h * 64;
    qf[s][0] = *(const bf16x8*)(qp + lg * 8);
    qf[s][1] = *(const bf16x8*)(qp + 32 + lg * 8);
  }

  f32x4 o[2][4];
#pragma unroll
  for (int s = 0; s < 2; s++)
#pragma unroll
    for (int i = 0; i < 4; i++) o[s][i] = (f32x4){0.f, 0.f, 0.f, 0.f};
  f32x4 lacc[2] = {(f32x4){0.f, 0.f, 0.f, 0.f}, (f32x4){0.f, 0.f, 0.f, 0.f}};

  const int r8 = l >> 3;
  const int c8g = (l & 7) ^ ((l >> 3) & 7);
  const bf16* Kbase = Kb + ((size_t)b * 1024) * 512 + h * 64 + c8g * 8;
  const bf16* Vbase = Vt + ((size_t)(b * 8 + h) * 64) * 1024 + c8g * 8;

  auto stage = [&](int buf, int t) {  // 4 gload16 per wave (8 waves cover both subtiles)
#pragma unroll
    for (int sub = 0; sub < 2; sub++) {
      const int kv0 = t * 128 + sub * 64;
      gload16(Kbase + (size_t)(kv0 + w * 8 + r8) * 512, &Ks[buf][sub][w * 8][0]);
      gload16(Vbase + (size_t)(w * 8 + r8) * 1024 + kv0, &Vs[buf][sub][w * 8][0]);
    }
  };

  if (w < 4) gload16(gfac + b * 1024 + w * 256 + l * 4, &gfs[w * 256]);
  stage(0, 0);
  VMC(0);
  BARR;

  for (int t = 0; t < 8; ++t) {
    const int buf = t & 1;
    if (t < 7) stage(buf ^ 1, t + 1);

#pragma unroll
    for (int sub = 0; sub < 2; sub++) {
      f32x4 gvv[4];
#pragma unroll
      for (int f = 0; f < 4; f++)
        gvv[f] = *(const f32x4*)(&gfs[t * 128 + sub * 64 + f * 16 + lg * 4]);

      // QK: S^T = K @ Q^T - SMREF (folded into acc init); row=key, col=q(lr)
      f32x4 s4[2][4];
      __builtin_amdgcn_s_setprio(1);
#pragma unroll
      for (int f = 0; f < 4; f++) {
        const int row = f * 16 + lr;
        const bf16x8 k0 = *(const bf16x8*)(&Ks[buf][sub][row][(lg ^ (row & 7)) * 8]);
        const bf16x8 k1 = *(const bf16x8*)(&Ks[buf][sub][row][((4 + lg) ^ (row & 7)) * 8]);
#pragma unroll
        for (int s = 0; s < 2; s++) {
          f32x4 z = (f32x4){-SMREF, -SMREF, -SMREF, -SMREF};
          z = __builtin_amdgcn_mfma_f32_16x16x32_bf16(k0, qf[s][0], z, 0, 0, 0);
          s4[s][f] = __builtin_amdgcn_mfma_f32_16x16x32_bf16(k1, qf[s][1], z, 0, 0, 0);
        }
      }
      __builtin_amdgcn_s_setprio(0);

      // p = exp2(s); l += p * gfac
      V8 pb[2][2];
#pragma unroll
      for (int s = 0; s < 2; s++) {
        float p[4][4];
#pragma unroll
        for (int f = 0; f < 4; f++)
#pragma unroll
          for (int r = 0; r < 4; r++) p[f][r] = EXP2F(s4[s][f][r]);
#pragma unroll
        for (int f = 0; f < 4; f++)
#pragma unroll
          for (int r = 0; r < 4; r++) lacc[s][r] = fmaf(p[f][r], gvv[f][r], lacc[s][r]);
        pb[s][0].u[0] = pk2(p[0][0], p[0][1]); pb[s][0].u[1] = pk2(p[0][2], p[0][3]);
        pb[s][0].u[2] = pk2(p[1][0], p[1][1]); pb[s][0].u[3] = pk2(p[1][2], p[1][3]);
        pb[s][1].u[0] = pk2(p[2][0], p[2][1]); pb[s][1].u[1] = pk2(p[2][2], p[2][3]);
        pb[s][1].u[2] = pk2(p[3][0], p[3][1]); pb[s][1].u[3] = pk2(p[3][2], p[3][3]);
      }

      __builtin_amdgcn_s_setprio(1);
#pragma unroll
      for (int od = 0; od < 4; od++) {
        const int row = od * 16 + lr;
        const bf16x8 va0 = *(const bf16x8*)(&Vs[buf][sub][row][(lg ^ (row & 7)) * 8]);
        const bf16x8 va1 = *(const bf16x8*)(&Vs[buf][sub][row][((4 + lg) ^ (row & 7)) * 8]);
#pragma unroll
        for (int s = 0; s < 2; s++) {
          o[s][od] = __builtin_amdgcn_mfma_f32_16x16x32_bf16(va0, pb[s][0].v, o[s][od], 0, 0, 0);
          o[s][od] = __builtin_amdgcn_mfma_f32_16x16x32_bf16(va1, pb[s][1].v, o[s][od], 0, 0, 0);
        }
      }
      __builtin_amdgcn_s_setprio(0);
    }

    if (t < 7) VMC(0);  // stage(t+1) issued a full chunk of compute ago
    BARR;               // WAR: all waves done reading buf before overwrite
  }

#pragma unroll
  for (int s = 0; s < 2; s++) {
    float lp = (lacc[s][0] + lacc[s][1]) + (lacc[s][2] + lacc[s][3]);
    lp += __shfl_xor(lp, 16);
    lp += __shfl_xor(lp, 32);
    const float inv = 1.0f / lp;
    bf16* cp = ctx + (size_t)(b * 512 + q0 + w * 32 + s * 16 + lr) * 512 + h * 64;
#pragma unroll
    for (int od = 0; od < 4; od++)
#pragma unroll
      for (int r = 0; r < 4; r++) cp[od * 16 + lg * 4 + r] = (bf16)(o[s][od][r] * inv);
  }
}

// ---------------------------------------------------------------------------
extern "C" void kernel_launch(void* const* d_in, const int* in_sizes, int n_in,
                              void* d_out, int out_size, void* d_ws, size_t ws_size,
                              hipStream_t stream) {
  (void)in_sizes; (void)n_in; (void)out_size; (void)ws_size;
  const float* Q_src = (const float*)d_in[0];
  const float* KV_src = (const float*)d_in[1];
  const float* gate = (const float*)d_in[2];
  const int* mask = (const int*)d_in[3];
  const float* Wq = (const float*)d_in[4];
  const float* bq = (const float*)d_in[5];
  const float* Wk = (const float*)d_in[6];
  const float* bk = (const float*)d_in[7];
  const float* Wv = (const float*)d_in[8];
  const float* bv = (const float*)d_in[9];
  const float* Wo = (const float*)d_in[10];
  const float* bo = (const float*)d_in[11];
  float* out = (float*)d_out;

  char* ws = (char*)d_ws;
  size_t off = 0;
  auto alloc = [&](size_t bytes) {
    char* p = ws + off;
    off += (bytes + 255) & ~(size_t)255;
    return p;
  };
  bf16* Wtq = (bf16*)alloc(512 * 512 * 2);
  bf16* Btkv = (bf16*)alloc(1024 * 512 * 2);
  bf16* Wto = (bf16*)alloc(512 * 512 * 2);
  float* gfac = (float*)alloc(16384 * 4);
  bf16* Qsb = (bf16*)alloc((size_t)8192 * 512 * 2);
  bf16* KVb = (bf16*)alloc((size_t)16384 * 512 * 2);  // reused as Cx after KV GEMM
  bf16* Qb = (bf16*)alloc((size_t)8192 * 512 * 2);
  bf16* Kb = (bf16*)alloc((size_t)16384 * 512 * 2);
  bf16* Vt = (bf16*)alloc((size_t)16384 * 512 * 2);
  bf16* Cx = KVb;

  prep_k<<<6464, 256, 0, stream>>>(Wq, Wk, Wv, Wo, Wtq, Btkv, Wto, gate, mask, gfac,
                                   Q_src, KV_src, Qsb, KVb);
  // K+V fused projection: [16384,512] @ [512,1024], 8-phase 256x256 tiles
  gemm_kv8<<<256, 512, 0, stream>>>(KVb, Btkv, bk, bv, gfac, Kb, Vt);
  // Q projection (scale folds softmax 1/6.4 and log2e)
  gemm_k<0, 4, 64><<<512, 256, 0, stream>>>(Qsb, Wtq, bq, Qb, SCQ2);
  attn_k<<<256, 512, 0, stream>>>(Qb, Kb, Vt, gfac, Cx);
  // O projection -> f32 out
  gemm_k<2, 4, 64><<<512, 256, 0, stream>>>(Cx, Wto, bo, out, 1.0f);
}